// Round 1
// baseline (384.975 us; speedup 1.0000x reference)
//
#include <hip/hip_runtime.h>
#include <hip/hip_bf16.h>

// ---------------------------------------------------------------------------
// GCN 2-layer forward: out = GCNConv(relu(GCNConv(x,W1,b1)), W2, b2)
// N=50000 nodes, E=800000 edges, F: 128 -> 128 -> 64, fp32.
// Pipeline: degree count -> exclusive scan (CSR rowptr) -> edge scatter (CSR)
//           -> GEMM1 -> aggregate+relu -> GEMM2 -> aggregate -> d_out
// ---------------------------------------------------------------------------

#define GCN_IN   128
#define GCN_H    128
#define GCN_OUT  64

// ---------------- degree count ----------------
__global__ void k_count(const int* __restrict__ dst, int* __restrict__ cnt, int E) {
    int e = blockIdx.x * 256 + threadIdx.x;
    if (e < E) atomicAdd(&cnt[dst[e]], 1);
}

// ---------------- single-block exclusive scan over cnt[n] -----------------
// writes rowptr[i] (exclusive), cursor[i] (copy), isd[i]=rsqrt(cnt+1), rowptr[n]
__global__ __launch_bounds__(1024) void k_scan(const int* __restrict__ cnt,
                                               int* __restrict__ rowptr,
                                               int* __restrict__ cursor,
                                               float* __restrict__ isd, int n) {
    __shared__ int wsum[16];
    __shared__ int carry;
    int tid = threadIdx.x;
    int lane = tid & 63;
    int wid = tid >> 6;
    if (tid == 0) carry = 0;
    __syncthreads();
    for (int base = 0; base < n; base += 1024) {
        int i = base + tid;
        int v = (i < n) ? cnt[i] : 0;
        // inclusive wave scan
        int s = v;
        #pragma unroll
        for (int off = 1; off < 64; off <<= 1) {
            int t = __shfl_up(s, off);
            if (lane >= off) s += t;
        }
        if (lane == 63) wsum[wid] = s;
        __syncthreads();                         // (A) wsum ready
        if (wid == 0 && lane < 16) {
            int ws = wsum[lane];
            #pragma unroll
            for (int off = 1; off < 16; off <<= 1) {
                int t = __shfl_up(ws, off);
                if (lane >= off) ws += t;
            }
            wsum[lane] = ws;                     // inclusive over waves
        }
        __syncthreads();                         // (B) wsum scanned
        int excl_wave = (wid == 0) ? 0 : wsum[wid - 1];
        int c = carry;
        int incl = s + excl_wave + c;
        int excl = incl - v;
        if (i < n) {
            rowptr[i] = excl;
            cursor[i] = excl;
            isd[i] = rsqrtf((float)(v + 1));     // deg includes self-loop
        }
        __syncthreads();                         // (C) all read carry/wsum
        if (tid == 1023) carry = incl;
    }
    __syncthreads();
    if (tid == 0) rowptr[n] = carry;
}

// ---------------- scatter edges into CSR buckets ----------------
__global__ void k_scatter(const int* __restrict__ src, const int* __restrict__ dst,
                          int* __restrict__ cursor, int* __restrict__ csr, int E) {
    int e = blockIdx.x * 256 + threadIdx.x;
    if (e < E) {
        int d = dst[e];
        int pos = atomicAdd(&cursor[d], 1);
        csr[pos] = src[e];
    }
}

// ---------------- fp32 GEMM: C[M x Ncols] = A[M x 128] * B[128 x Ncols] ----
// 64x64 tile, A transposed in LDS (pad 68 -> conflict-free b128 reads),
// 4x4 microtile per thread, 256 threads.
__global__ __launch_bounds__(256) void k_gemm(const float* __restrict__ A,
                                              const float* __restrict__ B,
                                              float* __restrict__ C,
                                              int M, int Ncols) {
    __shared__ float At[128][68];   // At[k][m]  (pad 68: 272B rows, 16B aligned)
    __shared__ float Bs[128][64];   // Bs[k][n]
    const int tid = threadIdx.x;
    const int row0 = blockIdx.x * 64;
    const int col0 = blockIdx.y * 64;

    // Load + transpose A tile: 64 rows x 128 k
    #pragma unroll
    for (int t = 0; t < 8; ++t) {
        int f = tid * 4 + t * 1024;      // 0..8188, step 4
        int r = f >> 7;                  // row in tile
        int k = f & 127;
        float4 v = make_float4(0.f, 0.f, 0.f, 0.f);
        int gr = row0 + r;
        if (gr < M) v = *(const float4*)(A + (size_t)gr * 128 + k);
        At[k + 0][r] = v.x;
        At[k + 1][r] = v.y;
        At[k + 2][r] = v.z;
        At[k + 3][r] = v.w;
    }
    // Load B tile: 128 x 64
    #pragma unroll
    for (int t = 0; t < 8; ++t) {
        int f = tid * 4 + t * 1024;
        int r = f >> 6;
        int c = f & 63;
        *(float4*)&Bs[r][c] = *(const float4*)(B + (size_t)r * Ncols + col0 + c);
    }
    __syncthreads();

    const int tx = tid & 15;
    const int ty = tid >> 4;
    float acc[4][4] = {};
    #pragma unroll 4
    for (int k = 0; k < 128; ++k) {
        float4 a = *(const float4*)&At[k][ty * 4];
        float4 b = *(const float4*)&Bs[k][tx * 4];
        acc[0][0] += a.x * b.x; acc[0][1] += a.x * b.y; acc[0][2] += a.x * b.z; acc[0][3] += a.x * b.w;
        acc[1][0] += a.y * b.x; acc[1][1] += a.y * b.y; acc[1][2] += a.y * b.z; acc[1][3] += a.y * b.w;
        acc[2][0] += a.z * b.x; acc[2][1] += a.z * b.y; acc[2][2] += a.z * b.z; acc[2][3] += a.z * b.w;
        acc[3][0] += a.w * b.x; acc[3][1] += a.w * b.y; acc[3][2] += a.w * b.z; acc[3][3] += a.w * b.w;
    }
    #pragma unroll
    for (int i = 0; i < 4; ++i) {
        int gr = row0 + ty * 4 + i;
        if (gr < M) {
            *(float4*)(C + (size_t)gr * Ncols + col0 + tx * 4) =
                make_float4(acc[i][0], acc[i][1], acc[i][2], acc[i][3]);
        }
    }
}

// ---------------- aggregation: one wave per node ----------------
// out[i] = isd_i * ( sum_{e in CSR(i)} isd[src]*h[src] + isd_i*h[i] ) + bias
template <int F, bool RELU>
__global__ __launch_bounds__(256) void k_agg(const float* __restrict__ h,
                                             const int* __restrict__ rowptr,
                                             const int* __restrict__ csr,
                                             const float* __restrict__ isd,
                                             const float* __restrict__ bias,
                                             float* __restrict__ out, int n) {
    int node = (blockIdx.x * 256 + threadIdx.x) >> 6;
    int lane = threadIdx.x & 63;
    if (node >= n) return;
    int beg = rowptr[node];
    int end = rowptr[node + 1];
    float isd_i = isd[node];

    if (F == 128) {
        const float* hb = h + 2 * lane;
        float2 acc = make_float2(0.f, 0.f);
        int e = beg;
        for (; e + 2 <= end; e += 2) {
            int s0 = csr[e];
            int s1 = csr[e + 1];
            float w0 = isd[s0];
            float w1 = isd[s1];
            float2 v0 = *(const float2*)(hb + (size_t)s0 * 128);
            float2 v1 = *(const float2*)(hb + (size_t)s1 * 128);
            acc.x += w0 * v0.x; acc.y += w0 * v0.y;
            acc.x += w1 * v1.x; acc.y += w1 * v1.y;
        }
        if (e < end) {
            int s0 = csr[e];
            float w0 = isd[s0];
            float2 v0 = *(const float2*)(hb + (size_t)s0 * 128);
            acc.x += w0 * v0.x; acc.y += w0 * v0.y;
        }
        float2 hv = *(const float2*)(hb + (size_t)node * 128);
        acc.x += isd_i * hv.x;
        acc.y += isd_i * hv.y;
        acc.x = acc.x * isd_i + bias[2 * lane];
        acc.y = acc.y * isd_i + bias[2 * lane + 1];
        if (RELU) {
            acc.x = fmaxf(acc.x, 0.f);
            acc.y = fmaxf(acc.y, 0.f);
        }
        *(float2*)(out + (size_t)node * 128 + 2 * lane) = acc;
    } else {
        const float* hb = h + lane;
        float acc = 0.f;
        int e = beg;
        for (; e + 2 <= end; e += 2) {
            int s0 = csr[e];
            int s1 = csr[e + 1];
            acc += isd[s0] * hb[(size_t)s0 * 64];
            acc += isd[s1] * hb[(size_t)s1 * 64];
        }
        if (e < end) {
            int s0 = csr[e];
            acc += isd[s0] * hb[(size_t)s0 * 64];
        }
        acc += isd_i * hb[(size_t)node * 64];
        acc = acc * isd_i + bias[lane];
        if (RELU) acc = fmaxf(acc, 0.f);
        out[(size_t)node * 64 + lane] = acc;
    }
}

static inline size_t align256(size_t x) { return (x + 255) & ~(size_t)255; }

extern "C" void kernel_launch(void* const* d_in, const int* in_sizes, int n_in,
                              void* d_out, int out_size, void* d_ws, size_t ws_size,
                              hipStream_t stream) {
    const float* x  = (const float*)d_in[0];
    const int*   ei = (const int*)d_in[1];
    const float* W1 = (const float*)d_in[2];
    const float* b1 = (const float*)d_in[3];
    const float* W2 = (const float*)d_in[4];
    const float* b2 = (const float*)d_in[5];
    float* out = (float*)d_out;

    const int N = in_sizes[0] / GCN_IN;   // 50000
    const int E = in_sizes[1] / 2;        // 800000
    const int* src = ei;
    const int* dst = ei + E;

    // workspace carve-up
    char* ws = (char*)d_ws;
    size_t o = 0;
    int*   cnt    = (int*)(ws + o);  o += align256((size_t)N * 4);
    int*   rowptr = (int*)(ws + o);  o += align256((size_t)(N + 1) * 4);
    int*   cursor = (int*)(ws + o);  o += align256((size_t)N * 4);
    int*   csr    = (int*)(ws + o);  o += align256((size_t)E * 4);
    float* isd    = (float*)(ws + o); o += align256((size_t)N * 4);
    float* hbuf   = (float*)(ws + o); o += align256((size_t)N * GCN_H * 4);
    float* h1buf  = (float*)(ws + o); o += align256((size_t)N * GCN_H * 4);
    // hbuf is reused as the layer-2 pre-aggregation buffer (N x 64)

    // 1. zero degree counts (ws is poisoned 0xAA before every timed launch)
    hipMemsetAsync(cnt, 0, (size_t)N * 4, stream);

    // 2. degree count
    k_count<<<(E + 255) / 256, 256, 0, stream>>>(dst, cnt, E);

    // 3. scan -> rowptr / cursor / isd
    k_scan<<<1, 1024, 0, stream>>>(cnt, rowptr, cursor, isd, N);

    // 4. scatter edges into CSR
    k_scatter<<<(E + 255) / 256, 256, 0, stream>>>(src, dst, cursor, csr, E);

    // 5. GEMM1: hbuf = x @ W1   [N x 128]
    {
        dim3 g((N + 63) / 64, GCN_H / 64);
        k_gemm<<<g, 256, 0, stream>>>(x, W1, hbuf, N, GCN_H);
    }

    // 6. aggregate + bias + relu -> h1buf
    k_agg<GCN_H, true><<<(N * 64 + 255) / 256, 256, 0, stream>>>(
        hbuf, rowptr, csr, isd, b1, h1buf, N);

    // 7. GEMM2: hbuf = h1buf @ W2   [N x 64]  (reuse hbuf)
    {
        dim3 g((N + 63) / 64, GCN_OUT / 64);
        k_gemm<<<g, 256, 0, stream>>>(h1buf, W2, hbuf, N, GCN_OUT);
    }

    // 8. aggregate + bias -> out
    k_agg<GCN_OUT, false><<<(N * 64 + 255) / 256, 256, 0, stream>>>(
        hbuf, rowptr, csr, isd, b2, out, N);
}

// Round 2
// 247.247 us; speedup vs baseline: 1.5570x; 1.5570x over previous
//
#include <hip/hip_runtime.h>
#include <hip/hip_bf16.h>

// ---------------------------------------------------------------------------
// GCN 2-layer forward, round 2.
// Changes vs round 1:
//  - CSR via fixed-capacity buckets (CAP=64) -> no single-block scan kernel.
//    Overflow edges (prob ~1e-17 for Poisson(16)) go to a list handled
//    correctly inside the agg kernels.
//  - Intermediate feature buffers (h, h1, h2) stored bf16 (RNE) -> halves the
//    dominant gather traffic. Accumulation stays fp32; final output fp32.
//  - Agg kernels: per-wave coalesced index/weight load + __shfl broadcast,
//    gathers unrolled x4 for deep vmcnt pipelining.
// ---------------------------------------------------------------------------

#define GCN_IN   128
#define GCN_H    128
#define GCN_OUT  64
#define CAP      64
#define OVF_CAP  65536

__device__ __forceinline__ ushort f2bf(float f) {     // fp32 -> bf16 RNE
    uint b = __float_as_uint(f);
    b = (b + 0x7FFFu + ((b >> 16) & 1u)) >> 16;
    return (ushort)b;
}
__device__ __forceinline__ float bf2f_lo(uint u) { return __uint_as_float(u << 16); }
__device__ __forceinline__ float bf2f_hi(uint u) { return __uint_as_float(u & 0xFFFF0000u); }
__device__ __forceinline__ float bf2f(ushort u) { return __uint_as_float(((uint)u) << 16); }

// ---------------- bucket-CSR build: count + scatter in one pass -------------
__global__ void k_scatter(const int* __restrict__ src, const int* __restrict__ dst,
                          int* __restrict__ cnt, int* __restrict__ slot,
                          int* __restrict__ ovfcnt, int2* __restrict__ ovf, int E) {
    int e = blockIdx.x * 256 + threadIdx.x;
    if (e >= E) return;
    int d = dst[e], s = src[e];
    int pos = atomicAdd(&cnt[d], 1);
    if (pos < CAP) {
        slot[(size_t)d * CAP + pos] = s;
    } else {
        int q = atomicAdd(ovfcnt, 1);
        if (q < OVF_CAP) ovf[q] = make_int2(d, s);
    }
}

__global__ void k_isd(const int* __restrict__ cnt, float* __restrict__ isd, int n) {
    int i = blockIdx.x * 256 + threadIdx.x;
    if (i < n) isd[i] = rsqrtf((float)(cnt[i] + 1));   // deg + self-loop
}

// ---------------- GEMM1: C_bf16[M x 128] = A_f32[M x 128] * B_f32[128 x 128]
// As kept row-major (scalar a-reads broadcast across tx -> conflict-free).
__global__ __launch_bounds__(256) void k_gemm1(const float* __restrict__ A,
                                               const float* __restrict__ B,
                                               ushort* __restrict__ C, int M) {
    __shared__ float As[64][128];
    __shared__ float Bs[128][64];
    const int tid = threadIdx.x;
    const int row0 = blockIdx.x * 64;
    const int col0 = blockIdx.y * 64;

    #pragma unroll
    for (int t = 0; t < 8; ++t) {
        int f = tid * 4 + t * 1024;
        int r = f >> 7;
        int k = f & 127;
        float4 v = make_float4(0.f, 0.f, 0.f, 0.f);
        int gr = row0 + r;
        if (gr < M) v = *(const float4*)(A + (size_t)gr * 128 + k);
        *(float4*)&As[r][k] = v;
    }
    #pragma unroll
    for (int t = 0; t < 8; ++t) {
        int f = tid * 4 + t * 1024;
        int r = f >> 6;
        int c = f & 63;
        *(float4*)&Bs[r][c] = *(const float4*)(B + (size_t)r * 128 + col0 + c);
    }
    __syncthreads();

    const int tx = tid & 15;
    const int ty = tid >> 4;
    float acc[4][4] = {};
    #pragma unroll 8
    for (int k = 0; k < 128; ++k) {
        float a0 = As[ty * 4 + 0][k];
        float a1 = As[ty * 4 + 1][k];
        float a2 = As[ty * 4 + 2][k];
        float a3 = As[ty * 4 + 3][k];
        float4 b = *(const float4*)&Bs[k][tx * 4];
        acc[0][0] += a0 * b.x; acc[0][1] += a0 * b.y; acc[0][2] += a0 * b.z; acc[0][3] += a0 * b.w;
        acc[1][0] += a1 * b.x; acc[1][1] += a1 * b.y; acc[1][2] += a1 * b.z; acc[1][3] += a1 * b.w;
        acc[2][0] += a2 * b.x; acc[2][1] += a2 * b.y; acc[2][2] += a2 * b.z; acc[2][3] += a2 * b.w;
        acc[3][0] += a3 * b.x; acc[3][1] += a3 * b.y; acc[3][2] += a3 * b.z; acc[3][3] += a3 * b.w;
    }
    #pragma unroll
    for (int i = 0; i < 4; ++i) {
        int gr = row0 + ty * 4 + i;
        if (gr < M) {
            ushort4 o;
            o.x = f2bf(acc[i][0]); o.y = f2bf(acc[i][1]);
            o.z = f2bf(acc[i][2]); o.w = f2bf(acc[i][3]);
            *(ushort4*)(C + (size_t)gr * 128 + col0 + tx * 4) = o;
        }
    }
}

// ---------------- GEMM2: C_bf16[M x 64] = A_bf16[M x 128] * B_f32[128 x 64]
__global__ __launch_bounds__(256) void k_gemm2(const ushort* __restrict__ A,
                                               const float* __restrict__ B,
                                               ushort* __restrict__ C, int M) {
    __shared__ float As[64][128];
    __shared__ float Bs[128][64];
    const int tid = threadIdx.x;
    const int row0 = blockIdx.x * 64;

    #pragma unroll
    for (int t = 0; t < 4; ++t) {
        int f = tid * 8 + t * 2048;
        int r = f >> 7;
        int k = f & 127;
        uint4 v = make_uint4(0u, 0u, 0u, 0u);
        int gr = row0 + r;
        if (gr < M) v = *(const uint4*)(A + (size_t)gr * 128 + k);  // 8 bf16
        As[r][k + 0] = bf2f_lo(v.x); As[r][k + 1] = bf2f_hi(v.x);
        As[r][k + 2] = bf2f_lo(v.y); As[r][k + 3] = bf2f_hi(v.y);
        As[r][k + 4] = bf2f_lo(v.z); As[r][k + 5] = bf2f_hi(v.z);
        As[r][k + 6] = bf2f_lo(v.w); As[r][k + 7] = bf2f_hi(v.w);
    }
    #pragma unroll
    for (int t = 0; t < 8; ++t) {
        int f = tid * 4 + t * 1024;
        int r = f >> 6;
        int c = f & 63;
        *(float4*)&Bs[r][c] = *(const float4*)(B + (size_t)r * 64 + c);
    }
    __syncthreads();

    const int tx = tid & 15;
    const int ty = tid >> 4;
    float acc[4][4] = {};
    #pragma unroll 8
    for (int k = 0; k < 128; ++k) {
        float a0 = As[ty * 4 + 0][k];
        float a1 = As[ty * 4 + 1][k];
        float a2 = As[ty * 4 + 2][k];
        float a3 = As[ty * 4 + 3][k];
        float4 b = *(const float4*)&Bs[k][tx * 4];
        acc[0][0] += a0 * b.x; acc[0][1] += a0 * b.y; acc[0][2] += a0 * b.z; acc[0][3] += a0 * b.w;
        acc[1][0] += a1 * b.x; acc[1][1] += a1 * b.y; acc[1][2] += a1 * b.z; acc[1][3] += a1 * b.w;
        acc[2][0] += a2 * b.x; acc[2][1] += a2 * b.y; acc[2][2] += a2 * b.z; acc[2][3] += a2 * b.w;
        acc[3][0] += a3 * b.x; acc[3][1] += a3 * b.y; acc[3][2] += a3 * b.z; acc[3][3] += a3 * b.w;
    }
    #pragma unroll
    for (int i = 0; i < 4; ++i) {
        int gr = row0 + ty * 4 + i;
        if (gr < M) {
            ushort4 o;
            o.x = f2bf(acc[i][0]); o.y = f2bf(acc[i][1]);
            o.z = f2bf(acc[i][2]); o.w = f2bf(acc[i][3]);
            *(ushort4*)(C + (size_t)gr * 64 + tx * 4) = o;
        }
    }
}

// ---------------- agg layer 1: F=128, bf16 in, bf16 out, +bias, relu --------
__global__ __launch_bounds__(256) void k_agg128(const ushort* __restrict__ h,
                                                const int* __restrict__ cnt,
                                                const int* __restrict__ slot,
                                                const float* __restrict__ isd,
                                                const float* __restrict__ bias,
                                                const int* __restrict__ ovfcnt,
                                                const int2* __restrict__ ovf,
                                                ushort* __restrict__ out, int n) {
    int node = (blockIdx.x * 256 + threadIdx.x) >> 6;
    int lane = threadIdx.x & 63;
    if (node >= n) return;
    int deg = cnt[node];
    int degm = min(deg, CAP);
    float isd_i = isd[node];
    int idx = slot[(size_t)node * CAP + lane];        // one coalesced 256B load
    bool valid = lane < degm;
    int sidx = valid ? idx : 0;
    float wl = valid ? isd[sidx] : 0.f;               // per-lane weight gather

    const ushort* hb = h + 2 * lane;
    float ax = 0.f, ay = 0.f;
    int j = 0;
    for (; j + 4 <= degm; j += 4) {
        int s0 = __shfl(sidx, j);     int s1 = __shfl(sidx, j + 1);
        int s2 = __shfl(sidx, j + 2); int s3 = __shfl(sidx, j + 3);
        float w0 = __shfl(wl, j);     float w1 = __shfl(wl, j + 1);
        float w2 = __shfl(wl, j + 2); float w3 = __shfl(wl, j + 3);
        uint v0 = *(const uint*)(hb + (size_t)s0 * 128);
        uint v1 = *(const uint*)(hb + (size_t)s1 * 128);
        uint v2 = *(const uint*)(hb + (size_t)s2 * 128);
        uint v3 = *(const uint*)(hb + (size_t)s3 * 128);
        ax += w0 * bf2f_lo(v0) + w1 * bf2f_lo(v1) + w2 * bf2f_lo(v2) + w3 * bf2f_lo(v3);
        ay += w0 * bf2f_hi(v0) + w1 * bf2f_hi(v1) + w2 * bf2f_hi(v2) + w3 * bf2f_hi(v3);
    }
    for (; j < degm; ++j) {
        int s0 = __shfl(sidx, j);
        float w0 = __shfl(wl, j);
        uint v0 = *(const uint*)(hb + (size_t)s0 * 128);
        ax += w0 * bf2f_lo(v0);
        ay += w0 * bf2f_hi(v0);
    }
    int ovn = *ovfcnt;                                 // ~always 0
    for (int q = 0; q < ovn; ++q) {
        int2 p = ovf[q];
        if (p.x == node) {
            float w0 = isd[p.y];
            uint v0 = *(const uint*)(hb + (size_t)p.y * 128);
            ax += w0 * bf2f_lo(v0);
            ay += w0 * bf2f_hi(v0);
        }
    }
    uint vs = *(const uint*)(hb + (size_t)node * 128); // self-loop
    ax += isd_i * bf2f_lo(vs);
    ay += isd_i * bf2f_hi(vs);
    ax = fmaxf(ax * isd_i + bias[2 * lane], 0.f);
    ay = fmaxf(ay * isd_i + bias[2 * lane + 1], 0.f);
    uint packed = (uint)f2bf(ax) | ((uint)f2bf(ay) << 16);
    *(uint*)(out + (size_t)node * 128 + 2 * lane) = packed;
}

// ---------------- agg layer 2: F=64, bf16 in, fp32 out, +bias ---------------
__global__ __launch_bounds__(256) void k_agg64(const ushort* __restrict__ h,
                                               const int* __restrict__ cnt,
                                               const int* __restrict__ slot,
                                               const float* __restrict__ isd,
                                               const float* __restrict__ bias,
                                               const int* __restrict__ ovfcnt,
                                               const int2* __restrict__ ovf,
                                               float* __restrict__ out, int n) {
    int node = (blockIdx.x * 256 + threadIdx.x) >> 6;
    int lane = threadIdx.x & 63;
    if (node >= n) return;
    int deg = cnt[node];
    int degm = min(deg, CAP);
    float isd_i = isd[node];
    int idx = slot[(size_t)node * CAP + lane];
    bool valid = lane < degm;
    int sidx = valid ? idx : 0;
    float wl = valid ? isd[sidx] : 0.f;

    const ushort* hb = h + lane;
    float acc = 0.f;
    int j = 0;
    for (; j + 4 <= degm; j += 4) {
        int s0 = __shfl(sidx, j);     int s1 = __shfl(sidx, j + 1);
        int s2 = __shfl(sidx, j + 2); int s3 = __shfl(sidx, j + 3);
        float w0 = __shfl(wl, j);     float w1 = __shfl(wl, j + 1);
        float w2 = __shfl(wl, j + 2); float w3 = __shfl(wl, j + 3);
        float v0 = bf2f(hb[(size_t)s0 * 64]);
        float v1 = bf2f(hb[(size_t)s1 * 64]);
        float v2 = bf2f(hb[(size_t)s2 * 64]);
        float v3 = bf2f(hb[(size_t)s3 * 64]);
        acc += w0 * v0 + w1 * v1 + w2 * v2 + w3 * v3;
    }
    for (; j < degm; ++j) {
        int s0 = __shfl(sidx, j);
        float w0 = __shfl(wl, j);
        acc += w0 * bf2f(hb[(size_t)s0 * 64]);
    }
    int ovn = *ovfcnt;
    for (int q = 0; q < ovn; ++q) {
        int2 p = ovf[q];
        if (p.x == node) acc += isd[p.y] * bf2f(hb[(size_t)p.y * 64]);
    }
    acc += isd_i * bf2f(hb[(size_t)node * 64]);
    out[(size_t)node * 64 + lane] = acc * isd_i + bias[lane];
}

static inline size_t align256(size_t x) { return (x + 255) & ~(size_t)255; }

extern "C" void kernel_launch(void* const* d_in, const int* in_sizes, int n_in,
                              void* d_out, int out_size, void* d_ws, size_t ws_size,
                              hipStream_t stream) {
    const float* x  = (const float*)d_in[0];
    const int*   ei = (const int*)d_in[1];
    const float* W1 = (const float*)d_in[2];
    const float* b1 = (const float*)d_in[3];
    const float* W2 = (const float*)d_in[4];
    const float* b2 = (const float*)d_in[5];
    float* out = (float*)d_out;

    const int N = in_sizes[0] / GCN_IN;   // 50000
    const int E = in_sizes[1] / 2;        // 800000
    const int* src = ei;
    const int* dst = ei + E;

    char* ws = (char*)d_ws;
    size_t o = 0;
    int*    cnt    = (int*)(ws + o);     o += align256((size_t)N * 4);
    int*    ovfcnt = (int*)(ws + o);     o += 256;
    int2*   ovf    = (int2*)(ws + o);    o += align256((size_t)OVF_CAP * 8);
    int*    slot   = (int*)(ws + o);     o += align256((size_t)N * CAP * 4);
    float*  isd    = (float*)(ws + o);   o += align256((size_t)N * 4);
    ushort* hb     = (ushort*)(ws + o);  o += align256((size_t)N * GCN_H * 2);
    ushort* h1b    = (ushort*)(ws + o);  o += align256((size_t)N * GCN_H * 2);
    ushort* h2b    = (ushort*)(ws + o);  o += align256((size_t)N * GCN_OUT * 2);

    // zero cnt + ovfcnt (contiguous)
    hipMemsetAsync(cnt, 0, align256((size_t)N * 4) + 256, stream);

    // bucket-CSR build
    k_scatter<<<(E + 255) / 256, 256, 0, stream>>>(src, dst, cnt, slot, ovfcnt, ovf, E);
    k_isd<<<(N + 255) / 256, 256, 0, stream>>>(cnt, isd, N);

    // layer 1
    {
        dim3 g((N + 63) / 64, GCN_H / 64);
        k_gemm1<<<g, 256, 0, stream>>>(x, W1, hb, N);
    }
    k_agg128<<<(N * 64 + 255) / 256, 256, 0, stream>>>(hb, cnt, slot, isd, b1,
                                                       ovfcnt, ovf, h1b, N);
    // layer 2
    k_gemm2<<<(N + 63) / 64, 256, 0, stream>>>(h1b, W2, h2b, N);
    k_agg64<<<(N * 64 + 255) / 256, 256, 0, stream>>>(h2b, cnt, slot, isd, b2,
                                                      ovfcnt, ovf, out, N);
}

// Round 3
// 241.040 us; speedup vs baseline: 1.5971x; 1.0258x over previous
//
#include <hip/hip_runtime.h>
#include <hip/hip_bf16.h>

// ---------------------------------------------------------------------------
// GCN 2-layer forward, round 3.
// Changes vs round 2:
//  - Heterogeneous fused kernel: scatter (CSR bucket build) + GEMM1 run as
//    disjoint block ranges of ONE launch -> scatter's latency-bound 58 us is
//    overlapped with GEMM1's VALU work. Scatter blocks come first (long pole).
//  - GEMMs rewritten with BK=32 K-chunks + transposed-A (pad 68) LDS layout:
//    17 KB LDS/block (was 64 KB) -> high co-resident occupancy, and
//    conflict-free inner-loop LDS reads (round 2 row-major As had 4-way).
//  - k_isd kernel + isd buffer deleted: aggs compute rsqrtf(cnt+1) inline.
//  - Nontemporal hints on streamed edge-list loads and scattered slot stores.
// ---------------------------------------------------------------------------

#define GCN_IN   128
#define GCN_H    128
#define GCN_OUT  64
#define CAP      64
#define OVF_CAP  65536
#define SCAT_BLOCKS 782   // ceil(800000 / (256*4)) -> 4 edges/thread

__device__ __forceinline__ ushort f2bf(float f) {     // fp32 -> bf16 RNE
    uint b = __float_as_uint(f);
    b = (b + 0x7FFFu + ((b >> 16) & 1u)) >> 16;
    return (ushort)b;
}
__device__ __forceinline__ float bf2f_lo(uint u) { return __uint_as_float(u << 16); }
__device__ __forceinline__ float bf2f_hi(uint u) { return __uint_as_float(u & 0xFFFF0000u); }
__device__ __forceinline__ float bf2f(ushort u) { return __uint_as_float(((uint)u) << 16); }

// ---------------- fused: [0,SCAT) = CSR bucket scatter, rest = GEMM1 --------
// GEMM1: C_bf16[M x 128] = A_f32[M x 128] * B_f32[128 x 128]
__global__ __launch_bounds__(256) void k_fused1(
        const int* __restrict__ src, const int* __restrict__ dst,
        int* __restrict__ cnt, int* __restrict__ slot,
        int* __restrict__ ovfcnt, int2* __restrict__ ovf, int E,
        const float* __restrict__ A, const float* __restrict__ B,
        ushort* __restrict__ C, int M) {
    __shared__ float At[32][68];   // At[k][m], pad 68 -> conflict-free b128
    __shared__ float Bs[32][64];
    const int tid = threadIdx.x;

    if (blockIdx.x < SCAT_BLOCKS) {
        // ---- scatter part: grid-stride, independent iterations ----
        const int stride = SCAT_BLOCKS * 256;
        for (int e = blockIdx.x * 256 + tid; e < E; e += stride) {
            int d = __builtin_nontemporal_load(dst + e);
            int s = __builtin_nontemporal_load(src + e);
            int pos = atomicAdd(&cnt[d], 1);
            if (pos < CAP) {
                __builtin_nontemporal_store(s, &slot[(size_t)d * CAP + pos]);
            } else {
                int q = atomicAdd(ovfcnt, 1);
                if (q < OVF_CAP) ovf[q] = make_int2(d, s);
            }
        }
        return;
    }

    // ---- GEMM1 part ----
    const int g = blockIdx.x - SCAT_BLOCKS;
    const int row0 = (g >> 1) * 64;
    const int col0 = (g & 1) * 64;
    const int tx = tid & 15;
    const int ty = tid >> 4;
    float acc[4][4] = {};

    for (int kb = 0; kb < 128; kb += 32) {
        // load+transpose A chunk: 64 rows x 32 k
        #pragma unroll
        for (int t = 0; t < 2; ++t) {
            int f = tid * 4 + t * 1024;
            int r = f >> 5;
            int k = f & 31;
            float4 v = make_float4(0.f, 0.f, 0.f, 0.f);
            int gr = row0 + r;
            if (gr < M) v = *(const float4*)(A + (size_t)gr * 128 + kb + k);
            At[k + 0][r] = v.x;
            At[k + 1][r] = v.y;
            At[k + 2][r] = v.z;
            At[k + 3][r] = v.w;
        }
        // load B chunk: 32 k x 64 cols
        #pragma unroll
        for (int t = 0; t < 2; ++t) {
            int f = tid * 4 + t * 1024;
            int r = f >> 6;
            int c = f & 63;
            *(float4*)&Bs[r][c] = *(const float4*)(B + (size_t)(kb + r) * 128 + col0 + c);
        }
        __syncthreads();
        #pragma unroll 8
        for (int k = 0; k < 32; ++k) {
            float4 a = *(const float4*)&At[k][ty * 4];
            float4 b = *(const float4*)&Bs[k][tx * 4];
            acc[0][0] += a.x * b.x; acc[0][1] += a.x * b.y; acc[0][2] += a.x * b.z; acc[0][3] += a.x * b.w;
            acc[1][0] += a.y * b.x; acc[1][1] += a.y * b.y; acc[1][2] += a.y * b.z; acc[1][3] += a.y * b.w;
            acc[2][0] += a.z * b.x; acc[2][1] += a.z * b.y; acc[2][2] += a.z * b.z; acc[2][3] += a.z * b.w;
            acc[3][0] += a.w * b.x; acc[3][1] += a.w * b.y; acc[3][2] += a.w * b.z; acc[3][3] += a.w * b.w;
        }
        __syncthreads();
    }
    #pragma unroll
    for (int i = 0; i < 4; ++i) {
        int gr = row0 + ty * 4 + i;
        if (gr < M) {
            ushort4 o;
            o.x = f2bf(acc[i][0]); o.y = f2bf(acc[i][1]);
            o.z = f2bf(acc[i][2]); o.w = f2bf(acc[i][3]);
            *(ushort4*)(C + (size_t)gr * 128 + col0 + tx * 4) = o;
        }
    }
}

// ---------------- GEMM2: C_bf16[M x 64] = A_bf16[M x 128] * B_f32[128 x 64]
__global__ __launch_bounds__(256) void k_gemm2(const ushort* __restrict__ A,
                                               const float* __restrict__ B,
                                               ushort* __restrict__ C, int M) {
    __shared__ float At[32][68];
    __shared__ float Bs[32][64];
    const int tid = threadIdx.x;
    const int row0 = blockIdx.x * 64;
    const int tx = tid & 15;
    const int ty = tid >> 4;
    float acc[4][4] = {};

    for (int kb = 0; kb < 128; kb += 32) {
        #pragma unroll
        for (int t = 0; t < 2; ++t) {
            int f = tid * 4 + t * 1024;
            int r = f >> 5;
            int k = f & 31;
            uint2 v = make_uint2(0u, 0u);    // 4 bf16
            int gr = row0 + r;
            if (gr < M) v = *(const uint2*)(A + (size_t)gr * 128 + kb + k);
            At[k + 0][r] = bf2f_lo(v.x);
            At[k + 1][r] = bf2f_hi(v.x);
            At[k + 2][r] = bf2f_lo(v.y);
            At[k + 3][r] = bf2f_hi(v.y);
        }
        #pragma unroll
        for (int t = 0; t < 2; ++t) {
            int f = tid * 4 + t * 1024;
            int r = f >> 6;
            int c = f & 63;
            *(float4*)&Bs[r][c] = *(const float4*)(B + (size_t)(kb + r) * 64 + c);
        }
        __syncthreads();
        #pragma unroll 8
        for (int k = 0; k < 32; ++k) {
            float4 a = *(const float4*)&At[k][ty * 4];
            float4 b = *(const float4*)&Bs[k][tx * 4];
            acc[0][0] += a.x * b.x; acc[0][1] += a.x * b.y; acc[0][2] += a.x * b.z; acc[0][3] += a.x * b.w;
            acc[1][0] += a.y * b.x; acc[1][1] += a.y * b.y; acc[1][2] += a.y * b.z; acc[1][3] += a.y * b.w;
            acc[2][0] += a.z * b.x; acc[2][1] += a.z * b.y; acc[2][2] += a.z * b.z; acc[2][3] += a.z * b.w;
            acc[3][0] += a.w * b.x; acc[3][1] += a.w * b.y; acc[3][2] += a.w * b.z; acc[3][3] += a.w * b.w;
        }
        __syncthreads();
    }
    #pragma unroll
    for (int i = 0; i < 4; ++i) {
        int gr = row0 + ty * 4 + i;
        if (gr < M) {
            ushort4 o;
            o.x = f2bf(acc[i][0]); o.y = f2bf(acc[i][1]);
            o.z = f2bf(acc[i][2]); o.w = f2bf(acc[i][3]);
            *(ushort4*)(C + (size_t)gr * 64 + tx * 4) = o;
        }
    }
}

// ---------------- agg layer 1: F=128, bf16 in/out, +bias, relu --------------
__global__ __launch_bounds__(256) void k_agg128(const ushort* __restrict__ h,
                                                const int* __restrict__ cnt,
                                                const int* __restrict__ slot,
                                                const float* __restrict__ bias,
                                                const int* __restrict__ ovfcnt,
                                                const int2* __restrict__ ovf,
                                                ushort* __restrict__ out, int n) {
    int node = (blockIdx.x * 256 + threadIdx.x) >> 6;
    int lane = threadIdx.x & 63;
    if (node >= n) return;
    int deg = cnt[node];
    int degm = min(deg, CAP);
    float isd_i = rsqrtf((float)(deg + 1));
    int idx = slot[(size_t)node * CAP + lane];        // one coalesced 256B load
    bool valid = lane < degm;
    int sidx = valid ? idx : 0;
    float wl = valid ? rsqrtf((float)(cnt[sidx] + 1)) : 0.f;

    const ushort* hb = h + 2 * lane;
    float ax = 0.f, ay = 0.f;
    int j = 0;
    for (; j + 4 <= degm; j += 4) {
        int s0 = __shfl(sidx, j);     int s1 = __shfl(sidx, j + 1);
        int s2 = __shfl(sidx, j + 2); int s3 = __shfl(sidx, j + 3);
        float w0 = __shfl(wl, j);     float w1 = __shfl(wl, j + 1);
        float w2 = __shfl(wl, j + 2); float w3 = __shfl(wl, j + 3);
        uint v0 = *(const uint*)(hb + (size_t)s0 * 128);
        uint v1 = *(const uint*)(hb + (size_t)s1 * 128);
        uint v2 = *(const uint*)(hb + (size_t)s2 * 128);
        uint v3 = *(const uint*)(hb + (size_t)s3 * 128);
        ax += w0 * bf2f_lo(v0) + w1 * bf2f_lo(v1) + w2 * bf2f_lo(v2) + w3 * bf2f_lo(v3);
        ay += w0 * bf2f_hi(v0) + w1 * bf2f_hi(v1) + w2 * bf2f_hi(v2) + w3 * bf2f_hi(v3);
    }
    for (; j < degm; ++j) {
        int s0 = __shfl(sidx, j);
        float w0 = __shfl(wl, j);
        uint v0 = *(const uint*)(hb + (size_t)s0 * 128);
        ax += w0 * bf2f_lo(v0);
        ay += w0 * bf2f_hi(v0);
    }
    int ovn = *ovfcnt;                                 // ~always 0
    for (int q = 0; q < ovn; ++q) {
        int2 p = ovf[q];
        if (p.x == node) {
            float w0 = rsqrtf((float)(cnt[p.y] + 1));
            uint v0 = *(const uint*)(hb + (size_t)p.y * 128);
            ax += w0 * bf2f_lo(v0);
            ay += w0 * bf2f_hi(v0);
        }
    }
    uint vs = *(const uint*)(hb + (size_t)node * 128); // self-loop
    ax += isd_i * bf2f_lo(vs);
    ay += isd_i * bf2f_hi(vs);
    ax = fmaxf(ax * isd_i + bias[2 * lane], 0.f);
    ay = fmaxf(ay * isd_i + bias[2 * lane + 1], 0.f);
    uint packed = (uint)f2bf(ax) | ((uint)f2bf(ay) << 16);
    *(uint*)(out + (size_t)node * 128 + 2 * lane) = packed;
}

// ---------------- agg layer 2: F=64, bf16 in, fp32 out, +bias ---------------
__global__ __launch_bounds__(256) void k_agg64(const ushort* __restrict__ h,
                                               const int* __restrict__ cnt,
                                               const int* __restrict__ slot,
                                               const float* __restrict__ bias,
                                               const int* __restrict__ ovfcnt,
                                               const int2* __restrict__ ovf,
                                               float* __restrict__ out, int n) {
    int node = (blockIdx.x * 256 + threadIdx.x) >> 6;
    int lane = threadIdx.x & 63;
    if (node >= n) return;
    int deg = cnt[node];
    int degm = min(deg, CAP);
    float isd_i = rsqrtf((float)(deg + 1));
    int idx = slot[(size_t)node * CAP + lane];
    bool valid = lane < degm;
    int sidx = valid ? idx : 0;
    float wl = valid ? rsqrtf((float)(cnt[sidx] + 1)) : 0.f;

    const ushort* hb = h + lane;
    float acc = 0.f;
    int j = 0;
    for (; j + 4 <= degm; j += 4) {
        int s0 = __shfl(sidx, j);     int s1 = __shfl(sidx, j + 1);
        int s2 = __shfl(sidx, j + 2); int s3 = __shfl(sidx, j + 3);
        float w0 = __shfl(wl, j);     float w1 = __shfl(wl, j + 1);
        float w2 = __shfl(wl, j + 2); float w3 = __shfl(wl, j + 3);
        float v0 = bf2f(hb[(size_t)s0 * 64]);
        float v1 = bf2f(hb[(size_t)s1 * 64]);
        float v2 = bf2f(hb[(size_t)s2 * 64]);
        float v3 = bf2f(hb[(size_t)s3 * 64]);
        acc += w0 * v0 + w1 * v1 + w2 * v2 + w3 * v3;
    }
    for (; j < degm; ++j) {
        int s0 = __shfl(sidx, j);
        float w0 = __shfl(wl, j);
        acc += w0 * bf2f(hb[(size_t)s0 * 64]);
    }
    int ovn = *ovfcnt;
    for (int q = 0; q < ovn; ++q) {
        int2 p = ovf[q];
        if (p.x == node) acc += rsqrtf((float)(cnt[p.y] + 1)) * bf2f(hb[(size_t)p.y * 64]);
    }
    acc += isd_i * bf2f(hb[(size_t)node * 64]);
    out[(size_t)node * 64 + lane] = acc * isd_i + bias[lane];
}

static inline size_t align256(size_t x) { return (x + 255) & ~(size_t)255; }

extern "C" void kernel_launch(void* const* d_in, const int* in_sizes, int n_in,
                              void* d_out, int out_size, void* d_ws, size_t ws_size,
                              hipStream_t stream) {
    const float* x  = (const float*)d_in[0];
    const int*   ei = (const int*)d_in[1];
    const float* W1 = (const float*)d_in[2];
    const float* b1 = (const float*)d_in[3];
    const float* W2 = (const float*)d_in[4];
    const float* b2 = (const float*)d_in[5];
    float* out = (float*)d_out;

    const int N = in_sizes[0] / GCN_IN;   // 50000
    const int E = in_sizes[1] / 2;        // 800000
    const int* src = ei;
    const int* dst = ei + E;

    char* ws = (char*)d_ws;
    size_t o = 0;
    int*    cnt    = (int*)(ws + o);     o += align256((size_t)N * 4);
    int*    ovfcnt = (int*)(ws + o);     o += 256;
    int2*   ovf    = (int2*)(ws + o);    o += align256((size_t)OVF_CAP * 8);
    int*    slot   = (int*)(ws + o);     o += align256((size_t)N * CAP * 4);
    ushort* hb     = (ushort*)(ws + o);  o += align256((size_t)N * GCN_H * 2);
    ushort* h1b    = (ushort*)(ws + o);  o += align256((size_t)N * GCN_H * 2);
    ushort* h2b    = (ushort*)(ws + o);  o += align256((size_t)N * GCN_OUT * 2);

    // zero cnt + ovfcnt (contiguous)
    hipMemsetAsync(cnt, 0, align256((size_t)N * 4) + 256, stream);

    // fused: scatter (blocks 0..781) || GEMM1 (blocks 782..2345)
    {
        int gemm_blocks = ((N + 63) / 64) * 2;         // 782 row-tiles x 2 col-tiles
        k_fused1<<<SCAT_BLOCKS + gemm_blocks, 256, 0, stream>>>(
            src, dst, cnt, slot, ovfcnt, ovf, E, x, W1, hb, N);
    }

    k_agg128<<<(N * 64 + 255) / 256, 256, 0, stream>>>(hb, cnt, slot, b1,
                                                       ovfcnt, ovf, h1b, N);
    k_gemm2<<<(N + 63) / 64, 256, 0, stream>>>(h1b, W2, h2b, N);
    k_agg64<<<(N * 64 + 255) / 256, 256, 0, stream>>>(h2b, cnt, slot, b2,
                                                      ovfcnt, ovf, out, N);
}